// Round 9
// baseline (51388.354 us; speedup 1.0000x reference)
//
#include <hip/hip_runtime.h>
#include <math.h>

typedef unsigned short u16;
typedef __attribute__((ext_vector_type(8))) short short8;
typedef __attribute__((ext_vector_type(4))) float f32x4;

__device__ __forceinline__ float sigm(float x) { return 1.0f / (1.0f + expf(-x)); }

__device__ __forceinline__ u16 f2bf(float x) {
    union { float f; unsigned u; } v; v.f = x;
    unsigned r = v.u + 0x7fffu + ((v.u >> 16) & 1u);
    return (u16)(r >> 16);
}
__device__ __forceinline__ float bf2f(u16 h) {
    union { unsigned u; float f; } v; v.u = ((unsigned)h) << 16;
    return v.f;
}
__device__ __forceinline__ f32x4 mfma16(short8 a, short8 b, f32x4 c) {
    return __builtin_amdgcn_mfma_f32_16x16x32_bf16(a, b, c, 0, 0, 0);
}

// ---------------------------------------------------------------------------
// k_step (R9): ZERO-SYNC variant. Ablation of the lockstep machinery that is
// common to every 21ms variant (R1-R8): no LDS W-staging, no s_barrier, no
// manual vmcnt. Each wave reads its MFMA B-fragments (W hi/lo) DIRECTLY from
// global (4 waves/block read the same 8KB slice -> L1 broadcast), A direct as
// before, and the compiler schedules its own counted waits while 8 resident
// waves/CU slip freely. Dead tail-overrun loads (were ~45% of FETCH) gone.
// Grid 512 (2 blocks/CU): dir=bid&1, rowhalf, colgrp (128 x 32 cols).
// Block tile 64 rows x 32 cols; 4 waves of 16 rows x 32 cols.
// Epilogue identical to R3 (ze is wave-local -> still no barrier).
// ---------------------------------------------------------------------------
__global__ __launch_bounds__(256, 2) void k_step(
    const u16* __restrict__ Ah, const u16* __restrict__ Al,
    u16* __restrict__ NAh, u16* __restrict__ NAl,
    const u16* __restrict__ WH, const u16* __restrict__ WL, int wstride,
    int koff_f, int nch_f, int koff_b, int nch_b,
    const float* __restrict__ BR, float* __restrict__ CF, float* __restrict__ CB,
    const float* __restrict__ Wfc1, const float* __restrict__ bfc1,
    float* __restrict__ out, int T, int t)
{
    __shared__ __align__(16) char ze[9216];    // z transpose (4 waves x 2304B)

    const int tid = threadIdx.x, bid = blockIdx.x;
    const int w = tid >> 6, lane = tid & 63, l15 = lane & 15, quad = lane >> 4;
    const int dir = bid & 1;
    const int rest = bid >> 1;
    const int rowhalf = rest >> 7, colgrp = rest & 127;
    const int nbase = dir * 4096 + colgrp * 32;
    const int koff = dir ? koff_b : koff_f;
    const int nch  = dir ? nch_b : nch_f;
    const int r0 = rowhalf * 64 + w * 16;      // this wave's 16 rows

    const bool fc1w = (t > 0) && (dir == 0) && (colgrp == 0);

    // direct B-fragment bases: col tile 0 -> nbase+l15, tile 1 -> +16
    const size_t wq = (size_t)(koff + quad * 8);
    const u16* WH0 = WH + (size_t)(nbase + l15) * wstride + wq;
    const u16* WH1 = WH + (size_t)(nbase + 16 + l15) * wstride + wq;
    const u16* WL0 = WL + (size_t)(nbase + l15) * wstride + wq;
    const u16* WL1 = WL + (size_t)(nbase + 16 + l15) * wstride + wq;

    // A fragment base (16 rows per wave)
    const size_t aoff = (size_t)(r0 + l15) * 2048 + (size_t)(koff + quad * 8);

    f32x4 acc0 = {}, acc1 = {};
    float fsum = 0.0f;

#pragma unroll 2
    for (int c = 0; c < nch; ++c) {
        const int kk = c * 64;
#pragma unroll
        for (int ks = 0; ks < 2; ++ks) {
            const int ko = kk + ks * 32;
            const short8 a_h = *(const short8*)(Ah + aoff + ko);
            const short8 a_l = *(const short8*)(Al + aoff + ko);
            const short8 bh0 = *(const short8*)(WH0 + ko);
            const short8 bh1 = *(const short8*)(WH1 + ko);
            const short8 bl0 = *(const short8*)(WL0 + ko);
            const short8 bl1 = *(const short8*)(WL1 + ko);
            acc0 = mfma16(a_h, bh0, acc0);
            acc0 = mfma16(a_l, bh0, acc0);
            acc0 = mfma16(a_h, bl0, acc0);
            acc1 = mfma16(a_h, bh1, acc1);
            acc1 = mfma16(a_l, bh1, acc1);
            acc1 = mfma16(a_h, bl1, acc1);
            if (fc1w) {
                const float* wp = Wfc1 + ko + quad * 8;
                const f32x4 w0 = *(const f32x4*)(wp);
                const f32x4 w1 = *(const f32x4*)(wp + 4);
#pragma unroll
                for (int e = 0; e < 8; ++e) {
                    const float v = bf2f((u16)a_h[e]) + bf2f((u16)a_l[e]);
                    const float wv = (e < 4) ? w0[e] : w1[e - 4];
                    fsum = fmaf(fmaxf(v, 0.0f), wv, fsum);
                }
            }
        }
    }

    // fc1 reduce + store (register-only; sums the 4 quads of each l15 row)
    if (fc1w) {
        float v = fsum;
        v += __shfl_xor(v, 16);
        v += __shfl_xor(v, 32);
        if (lane < 16)
            out[(size_t)(r0 + l15) * T + (t - 1)] = v + bfc1[0];
    }

    // z tile -> per-wave LDS transpose (wave-local region, no barrier)
    char* zb = ze + w * 2304;
#pragma unroll
    for (int r = 0; r < 4; ++r) {
        *(float*)(zb + (quad * 4 + r) * 144 + l15 * 4) = acc0[r];
        *(float*)(zb + (quad * 4 + r) * 144 + (16 + l15) * 4) = acc1[r];
    }

    float* C = dir ? CB : CF;
    const int ul = lane & 7;
#pragma unroll
    for (int p2 = 0; p2 < 2; ++p2) {
        const int ml = p2 * 8 + (lane >> 3);
        const f32x4 z = *(const f32x4*)(zb + ml * 144 + ul * 16);
        const f32x4 b4 = *(const f32x4*)(BR + nbase + ul * 4);
        const float zi = z[0] + b4[0], zf = z[1] + b4[1];
        const float zg = z[2] + b4[2], zo = z[3] + b4[3];
        const int u = colgrp * 8 + ul;
        const int m = r0 + ml;
        const size_t cidx = (size_t)m * 1024 + u;
        const float cold = C[cidx];
        const float c2 = sigm(zf) * cold + sigm(zi) * tanhf(zg);
        const float h2 = sigm(zo) * tanhf(c2);
        C[cidx] = c2;
        const size_t hidx = (size_t)m * 2048 + dir * 1024 + u;
        const u16 hh = f2bf(h2);
        NAh[hidx] = hh;
        NAl[hidx] = f2bf(h2 - bf2f(hh));
    }
}

// ---------------------------------------------------------------------------
// k_tail: out[:, T-1] from final A planes. 128 blocks (one per row).
// ---------------------------------------------------------------------------
__global__ __launch_bounds__(256) void k_tail(
    const u16* __restrict__ Ah, const u16* __restrict__ Al,
    const float* __restrict__ Wfc1, const float* __restrict__ bfc1,
    float* __restrict__ out, int T)
{
    __shared__ float red[256];
    const int m = blockIdx.x, tid = threadIdx.x;
    const size_t base = (size_t)m * 2048 + tid * 8;
    const short8 hv = *(const short8*)(Ah + base);
    const short8 lv = *(const short8*)(Al + base);
    float s = 0.0f;
#pragma unroll
    for (int e = 0; e < 8; ++e) {
        const float v = bf2f((u16)hv[e]) + bf2f((u16)lv[e]);
        s = fmaf(fmaxf(v, 0.0f), Wfc1[tid * 8 + e], s);
    }
    red[tid] = s;
    __syncthreads();
    for (int off = 128; off > 0; off >>= 1) {
        if (tid < off) red[tid] += red[tid + off];
        __syncthreads();
    }
    if (tid == 0) out[(size_t)m * T + T - 1] = red[0] + bfc1[0];
}

// ---------------------------------------------------------------------------
// k_fold: W'[col'][1024+j] = (Wih' @ WoT^T)[col'][j]  (+ Whh_b for bwd cols)
// ---------------------------------------------------------------------------
__global__ __launch_bounds__(256, 1) void k_fold(
    const u16* __restrict__ AH, const u16* __restrict__ AL,   // Wih' 8192x512
    const u16* __restrict__ BH, const u16* __restrict__ BL,   // WoT 1024x512
    const float* __restrict__ Whh_b,
    u16* __restrict__ WH, u16* __restrict__ WL)
{
    const int tid = threadIdx.x, bid = blockIdx.x;
    const int w = tid >> 6, lane = tid & 63, l15 = lane & 15, quad = lane >> 4;
    const int bm = bid >> 4, bn = bid & 15;
    const int ar0 = bm * 64 + (w & 1) * 32;
    const int br0 = bn * 64 + (w >> 1) * 32;
    f32x4 acc[2][2] = {};
    for (int k0 = 0; k0 < 512; k0 += 32) {
        short8 a_h[2], a_l[2], b_h[2], b_l[2];
#pragma unroll
        for (int mt = 0; mt < 2; ++mt) {
            const size_t o = (size_t)(ar0 + mt * 16 + l15) * 512 + k0 + quad * 8;
            a_h[mt] = *(const short8*)(AH + o);
            a_l[mt] = *(const short8*)(AL + o);
        }
#pragma unroll
        for (int nt = 0; nt < 2; ++nt) {
            const size_t o = (size_t)(br0 + nt * 16 + l15) * 512 + k0 + quad * 8;
            b_h[nt] = *(const short8*)(BH + o);
            b_l[nt] = *(const short8*)(BL + o);
        }
#pragma unroll
        for (int mt = 0; mt < 2; ++mt)
#pragma unroll
            for (int nt = 0; nt < 2; ++nt) {
                acc[mt][nt] = mfma16(a_h[mt], b_h[nt], acc[mt][nt]);
                acc[mt][nt] = mfma16(a_l[mt], b_h[nt], acc[mt][nt]);
                acc[mt][nt] = mfma16(a_h[mt], b_l[nt], acc[mt][nt]);
            }
    }
#pragma unroll
    for (int mt = 0; mt < 2; ++mt)
#pragma unroll
        for (int nt = 0; nt < 2; ++nt)
#pragma unroll
            for (int r = 0; r < 4; ++r) {
                const int row = ar0 + mt * 16 + quad * 4 + r;   // col'
                const int j = br0 + nt * 16 + l15;
                float v = acc[mt][nt][r];
                if (row >= 4096)
                    v += Whh_b[(size_t)((row & 3) * 1024 + ((row & 4095) >> 2)) * 1024 + j];
                const size_t d = (size_t)row * 2048 + 1024 + j;
                const u16 hh = f2bf(v);
                WH[d] = hh;
                WL[d] = f2bf(v - bf2f(hh));
            }
}

// ---------------------------------------------------------------------------
// k_prep: Wih' hi/lo, WoT hi/lo, BR0/BR1, A0 (x=dec), out=b_fc1, Whh_f -> W'.
// ---------------------------------------------------------------------------
__global__ __launch_bounds__(256) void k_prep(
    const float* __restrict__ dec,
    const float* __restrict__ Wih_f, const float* __restrict__ Whh_f,
    const float* __restrict__ b_f, const float* __restrict__ Wih_b,
    const float* __restrict__ b_b, const float* __restrict__ W_out,
    const float* __restrict__ b_out, const float* __restrict__ b_fc1,
    u16* __restrict__ WihH, u16* __restrict__ WihL,
    u16* __restrict__ WoTH, u16* __restrict__ WoTL,
    float* __restrict__ BR0, float* __restrict__ BR1,
    u16* __restrict__ A0h, u16* __restrict__ A0l,
    u16* __restrict__ WH, u16* __restrict__ WL,
    float* __restrict__ out, int out_size)
{
    const int t = blockIdx.x * 256 + threadIdx.x;
    if (t < 524288) {                       // Wih' (gate-interleaved cols, K=512)
        const int colp = t >> 6, kb = (t & 63) * 8;
        const int dir = colp >> 12, u = (colp & 4095) >> 2, g = colp & 3;
        const float* src = (dir ? Wih_b : Wih_f) + (size_t)(g * 1024 + u) * 512 + kb;
        const size_t d = (size_t)colp * 512 + kb;
#pragma unroll
        for (int j = 0; j < 8; ++j) {
            const float v = src[j];
            const u16 hh = f2bf(v);
            WihH[d + j] = hh; WihL[d + j] = f2bf(v - bf2f(hh));
        }
    } else if (t < 589824) {                // WoT[j][l] = W_out[l][j]
        const int i = t - 524288, jc = i >> 6, lb = (i & 63) * 8;
#pragma unroll
        for (int jj = 0; jj < 8; ++jj) {
            const float v = W_out[(size_t)(lb + jj) * 1024 + jc];
            const size_t d = (size_t)jc * 512 + lb + jj;
            const u16 hh = f2bf(v);
            WoTH[d] = hh; WoTL[d] = f2bf(v - bf2f(hh));
        }
    } else if (t < 598016) {                // biases
        const int colp = t - 589824;
        const int dir = colp >> 12, u = (colp & 4095) >> 2, g = colp & 3;
        const float* Wih = dir ? Wih_b : Wih_f;
        const float s = (dir ? b_b : b_f)[g * 1024 + u];
        BR0[colp] = s;
        float dot = 0.0f;
        for (int l = 0; l < 512; ++l)
            dot += Wih[(size_t)(g * 1024 + u) * 512 + l] * b_out[l];
        BR1[colp] = s + dot;
    } else if (t < 606208) {                // A0 = dec (cols [0,512), stride 2048)
        const int i = t - 598016, m = i >> 6, kb = (i & 63) * 8;
#pragma unroll
        for (int j = 0; j < 8; ++j) {
            const float v = dec[(size_t)m * 512 + kb + j];
            const size_t d = (size_t)m * 2048 + kb + j;
            const u16 hh = f2bf(v);
            A0h[d] = hh; A0l[d] = f2bf(v - bf2f(hh));
        }
    } else if (t < 614400) {                // out init = b_fc1 (safety net)
        const int base = (t - 606208) * 8;
        const float b0 = b_fc1[0];
#pragma unroll
        for (int j = 0; j < 8; ++j)
            if (base + j < out_size) out[base + j] = b0;
    } else {                                // Whh_f -> W' fwd cols, k in [0,1024)
        const int i = t - 614400, colp = i >> 7, kb = (i & 127) * 8;
        const int u = colp >> 2, g = colp & 3;
        const float* src = Whh_f + (size_t)(g * 1024 + u) * 1024 + kb;
        const size_t d = (size_t)colp * 2048 + kb;
#pragma unroll
        for (int j = 0; j < 8; ++j) {
            const float v = src[j];
            const u16 hh = f2bf(v);
            WH[d + j] = hh; WL[d + j] = f2bf(v - bf2f(hh));
        }
    }
}

// ---------------------------------------------------------------------------
// ws layout = baseline.
// ---------------------------------------------------------------------------
extern "C" void kernel_launch(void* const* d_in, const int* in_sizes, int n_in,
                              void* d_out, int out_size, void* d_ws, size_t ws_size,
                              hipStream_t stream) {
    const float* dec   = (const float*)d_in[0];
    const float* Wih_f = (const float*)d_in[2];
    const float* Whh_f = (const float*)d_in[3];
    const float* b_f   = (const float*)d_in[4];
    const float* Wih_b = (const float*)d_in[5];
    const float* Whh_b = (const float*)d_in[6];
    const float* b_b   = (const float*)d_in[7];
    const float* W_out = (const float*)d_in[8];
    const float* b_out = (const float*)d_in[9];
    const float* W_fc1 = (const float*)d_in[10];
    const float* b_fc1 = (const float*)d_in[11];
    float* out = (float*)d_out;

    char* ws = (char*)d_ws;
    u16* WH    = (u16*)(ws);
    u16* WL    = (u16*)(ws + 33554432);
    u16* WihH  = (u16*)(ws + 67108864);
    u16* WihL  = (u16*)(ws + 75497472);
    u16* WoTH  = (u16*)(ws + 83886080);
    u16* WoTL  = (u16*)(ws + 84934656);
    u16* A0h   = (u16*)(ws + 85983232);
    u16* A0l   = (u16*)(ws + 86507520);
    u16* A1h   = (u16*)(ws + 87031808);
    u16* A1l   = (u16*)(ws + 87556096);
    float* CF  = (float*)(ws + 88080384);
    float* CB  = (float*)(ws + 88604672);
    float* BR0 = (float*)(ws + 89128960);
    float* BR1 = (float*)(ws + 89161728);

    k_prep<<<4448, 256, 0, stream>>>(dec, Wih_f, Whh_f, b_f, Wih_b, b_b,
                                     W_out, b_out, b_fc1,
                                     WihH, WihL, WoTH, WoTL, BR0, BR1,
                                     A0h, A0l, WH, WL, out, out_size);
    k_fold<<<2048, 256, 0, stream>>>(WihH, WihL, WoTH, WoTL, Whh_b, WH, WL);
    hipMemsetAsync(CF, 0, 1048576, stream);   // CF + CB contiguous

    const int T = out_size / 128;
    u16* Abh[2] = {A0h, A1h};
    u16* Abl[2] = {A0l, A1l};
    for (int t = 0; t < T; ++t) {
        const int in = t & 1, nx = in ^ 1;
        if (t == 0) {
            k_step<<<512, 256, 0, stream>>>(A0h, A0l, A1h, A1l,
                                            WihH, WihL, 512, 0, 8, 0, 8,
                                            BR0, CF, CB, W_fc1, b_fc1, out, T, 0);
        } else {
            k_step<<<512, 256, 0, stream>>>(Abh[in], Abl[in], Abh[nx], Abl[nx],
                                            WH, WL, 2048, 0, 32, 1024, 16,
                                            BR1, CF, CB, W_fc1, b_fc1, out, T, t);
        }
    }
    k_tail<<<128, 256, 0, stream>>>(Abh[T & 1], Abl[T & 1], W_fc1, b_fc1, out, T);
}

// Round 10
// 18792.438 us; speedup vs baseline: 2.7345x; 2.7345x over previous
//
#include <hip/hip_runtime.h>
#include <math.h>

typedef unsigned short u16;
typedef __attribute__((ext_vector_type(8))) short short8;
typedef __attribute__((ext_vector_type(4))) float f32x4;

__device__ __forceinline__ float sigm(float x) { return 1.0f / (1.0f + expf(-x)); }

__device__ __forceinline__ u16 f2bf(float x) {
    union { float f; unsigned u; } v; v.f = x;
    unsigned r = v.u + 0x7fffu + ((v.u >> 16) & 1u);
    return (u16)(r >> 16);
}
__device__ __forceinline__ float bf2f(u16 h) {
    union { unsigned u; float f; } v; v.u = ((unsigned)h) << 16;
    return v.f;
}
__device__ __forceinline__ f32x4 mfma16(short8 a, short8 b, f32x4 c) {
    return __builtin_amdgcn_mfma_f32_16x16x32_bf16(a, b, c, 0, 0, 0);
}
__device__ __forceinline__ void gl_lds16(const void* g, void* l) {
    __builtin_amdgcn_global_load_lds(
        (const __attribute__((address_space(1))) unsigned int*)g,
        (__attribute__((address_space(3))) unsigned int*)l, 16, 0, 0);
}
__device__ __forceinline__ int swz(int c) { return (c ^ (c >> 2)) & 3; }

// ---------------------------------------------------------------------------
// k_step: ONE kernel per timestep. R10 = R3 (best, 20.79ms) + WORK BALANCE:
//  (1) dir = bid>>8 (was bid&1). Round-robin bid%8->XCD means dir=bid&1 put
//      all heavy fwd blocks (K=2048) on even XCDs and light bwd (K=1024) on
//      odd XCDs -> half the chip did 2/3 of the work every step, R1-R9.
//      Now fwd=bids 0..255, bwd=256..511: every XCD gets 16+16, every CU
//      pairs 1 fwd + 1 bwd (dispatch fills slot1 with fwd, slot2 with bwd).
//  (2) fc1 duty moved from fwd-colgrp0 (straggler on the heavy half) to
//      bwd-colgrp0 (light half): in-loop part covers k in [1024,2048) via
//      its own A-frags; post-loop A-only scan adds k in [0,1024) (no W, no
//      MFMA, no barrier - workgroup-local, fills bwd idle time).
// Pipeline machinery identical to R3: 4 LDS bufs, stage+A 3 chunks ahead,
// counted s_waitcnt vmcnt(16), order pinned by empty-asm fences.
// ---------------------------------------------------------------------------
#define FENCE() asm volatile("" ::: "memory")

#define STAGE_W(kk, buf)                                                      \
    do {                                                                      \
        gl_lds16(Wsrc + sA + (kk), sm + (buf) * 8192 + lds0);                 \
        gl_lds16(Wsrc + sB + (kk), sm + (buf) * 8192 + lds1);                 \
    } while (0)

#define LOAD_A(kk, AH_, AL_)                                                  \
    do {                                                                      \
        _Pragma("unroll") for (int ks_ = 0; ks_ < 2; ++ks_) {                 \
            AH_[ks_] = *(const short8*)(Ah + aoff + (kk) + ks_ * 32);         \
            AL_[ks_] = *(const short8*)(Al + aoff + (kk) + ks_ * 32);         \
        }                                                                     \
    } while (0)

#define COMPUTE(bix, AH_, AL_, cix)                                           \
    do {                                                                      \
        const char* bb_ = sm + (bix) * 8192;                                  \
        _Pragma("unroll") for (int ks_ = 0; ks_ < 2; ++ks_) {                 \
            short8 bh_[2], bl_[2];                                            \
            _Pragma("unroll") for (int nt_ = 0; nt_ < 2; ++nt_) {             \
                const int col_ = nt_ * 16 + l15;                              \
                const int off_ = ks_ * 2048 + col_ * 64 + ((quad ^ swz(col_)) * 16); \
                bh_[nt_] = *(const short8*)(bb_ + off_);                      \
                bl_[nt_] = *(const short8*)(bb_ + 4096 + off_);               \
            }                                                                 \
            _Pragma("unroll") for (int nt_ = 0; nt_ < 2; ++nt_) {             \
                acc[nt_] = mfma16(AH_[ks_], bh_[nt_], acc[nt_]);              \
                acc[nt_] = mfma16(AL_[ks_], bh_[nt_], acc[nt_]);              \
                acc[nt_] = mfma16(AH_[ks_], bl_[nt_], acc[nt_]);              \
            }                                                                 \
        }                                                                     \
        if (fc1w) {                                                           \
            const int kb_ = koff + (cix) * 64 + quad * 8;                     \
            _Pragma("unroll") for (int ks_ = 0; ks_ < 2; ++ks_) {             \
                const float* wp_ = smWf + kb_ + ks_ * 32;                     \
                const f32x4 w0_ = *(const f32x4*)(wp_);                       \
                const f32x4 w1_ = *(const f32x4*)(wp_ + 4);                   \
                const short8 hv_ = AH_[ks_];                                  \
                const short8 lv_ = AL_[ks_];                                  \
                _Pragma("unroll") for (int e_ = 0; e_ < 8; ++e_) {            \
                    const float v_ = bf2f((u16)hv_[e_]) + bf2f((u16)lv_[e_]); \
                    const float wv_ = (e_ < 4) ? w0_[e_] : w1_[e_ - 4];       \
                    fsum = fmaf(fmaxf(v_, 0.0f), wv_, fsum);                  \
                }                                                             \
            }                                                                 \
        }                                                                     \
    } while (0)

// One pipelined chunk: wait own stage(c) done -> barrier (all waves' parts
// done) -> fence -> issue stage(c+3) -> fence (pin S before A in vmcnt
// order) -> issue A(c+3) -> compute chunk c.
#define ITER(cc, BC, BS, AHU, ALU, AHL, ALL)                                  \
    do {                                                                      \
        asm volatile("s_waitcnt vmcnt(16)" ::: "memory");                     \
        __builtin_amdgcn_s_barrier();                                         \
        FENCE();                                                              \
        STAGE_W(((cc) + 3) * 64, BS);                                         \
        FENCE();                                                              \
        LOAD_A(((cc) + 3) * 64, AHL, ALL);                                    \
        COMPUTE(BC, AHU, ALU, (cc));                                          \
    } while (0)

__global__ __launch_bounds__(256, 2) void k_step(
    const u16* __restrict__ Ah, const u16* __restrict__ Al,
    u16* __restrict__ NAh, u16* __restrict__ NAl,
    const u16* __restrict__ WH, const u16* __restrict__ WL, int wstride,
    int koff_f, int nch_f, int koff_b, int nch_b,
    const float* __restrict__ BR, float* __restrict__ CF, float* __restrict__ CB,
    const float* __restrict__ Wfc1, const float* __restrict__ bfc1,
    float* __restrict__ out, int T, int t)
{
    __shared__ __align__(16) char sm[32768];   // 4 x 8KB W staging bufs
    __shared__ __align__(16) char ze[9216];    // epilogue z transpose (per wave)
    __shared__ __align__(16) float smWf[2048]; // Wfc1 (fc1 blocks only)

    const int tid = threadIdx.x, bid = blockIdx.x;
    const int w = tid >> 6, lane = tid & 63, l15 = lane & 15, quad = lane >> 4;
    const int dir = bid >> 8;                  // 0..255 fwd, 256..511 bwd
    const int rest = bid & 255;
    const int rowhalf = rest >> 7, colgrp = rest & 127;
    const int nbase = dir * 4096 + colgrp * 32;
    const int koff = dir ? koff_b : koff_f;
    const int nch  = dir ? nch_b : nch_f;
    const int r0 = rowhalf * 64 + w * 16;      // this wave's 16 rows

    // fc1 duty: BWD colgrp-0 blocks (light half), both rowhalves, t>0
    const bool fc1b = (dir == 1) && (colgrp == 0);
    const bool fc1w = fc1b && (t > 0);

    // staging role: plane sp (0 hi, 1 lo), k-half skh
    const int sp = w >> 1, skh = w & 1;
    const u16* Wsrc = sp ? WL : WH;
    size_t sA, sB;
    int lds0, lds1;
    {
        const int colA = 0 * 16 + (lane >> 2);
        const int colB = 1 * 16 + (lane >> 2);
        const int sa = (lane & 3) ^ swz(colA);
        const int sb = (lane & 3) ^ swz(colB);
        sA = (size_t)(nbase + colA) * wstride + (size_t)(koff + skh * 32 + sa * 8);
        sB = (size_t)(nbase + colB) * wstride + (size_t)(koff + skh * 32 + sb * 8);
        lds0 = sp * 4096 + skh * 2048;
        lds1 = lds0 + 1024;
    }

    // A fragment base (16 rows per wave)
    const size_t aoff = (size_t)(r0 + l15) * 2048 + (size_t)(koff + quad * 8);

    f32x4 acc[2] = {};
    short8 ah0[2], al0[2], ah1[2], al1[2];     // 4 static A reg sets
    short8 ah2[2], al2[2], ah3[2], al3[2];
    float fsum = 0.0f;

    // Wfc1 -> LDS (fc1 blocks; completes before the vmcnt pattern starts)
    if (fc1b) {
        const f32x4 w0 = *(const f32x4*)(Wfc1 + tid * 8);
        const f32x4 w1 = *(const f32x4*)(Wfc1 + tid * 8 + 4);
        *(f32x4*)(smWf + tid * 8) = w0;
        *(f32x4*)(smWf + tid * 8 + 4) = w1;
    }
    asm volatile("s_waitcnt vmcnt(0) lgkmcnt(0)" ::: "memory");

    // prologue: interleaved S/A issue, order pinned: S0,A0,S1,A1,S2,A2
    STAGE_W(0, 0);   FENCE(); LOAD_A(0, ah0, al0);   FENCE();
    STAGE_W(64, 1);  FENCE(); LOAD_A(64, ah1, al1);  FENCE();
    STAGE_W(128, 2); FENCE(); LOAD_A(128, ah2, al2); FENCE();

    for (int c = 0; c < nch; c += 4) {          // nch in {8,16,32}
        ITER(c + 0, 0, 3, ah0, al0, ah3, al3);
        ITER(c + 1, 1, 0, ah1, al1, ah0, al0);
        ITER(c + 2, 2, 1, ah2, al2, ah1, al1);
        ITER(c + 3, 3, 2, ah3, al3, ah2, al2);
    }
    asm volatile("s_waitcnt vmcnt(0)" ::: "memory");  // drain dead tail loads

    // fc1: add the fwd-h part (k in [0,1024)) via cheap A-only scan, then
    // reduce + store. Workgroup-local; runs while other blocks still GEMM.
    if (fc1w) {
        const size_t af = (size_t)(r0 + l15) * 2048 + (size_t)(quad * 8);
        for (int c2 = 0; c2 < 16; ++c2) {
#pragma unroll
            for (int ks = 0; ks < 2; ++ks) {
                const int ko = c2 * 64 + ks * 32;
                const short8 hv = *(const short8*)(Ah + af + ko);
                const short8 lv = *(const short8*)(Al + af + ko);
                const float* wp = smWf + ko + quad * 8;
                const f32x4 w0 = *(const f32x4*)(wp);
                const f32x4 w1 = *(const f32x4*)(wp + 4);
#pragma unroll
                for (int e = 0; e < 8; ++e) {
                    const float v = bf2f((u16)hv[e]) + bf2f((u16)lv[e]);
                    const float wv = (e < 4) ? w0[e] : w1[e - 4];
                    fsum = fmaf(fmaxf(v, 0.0f), wv, fsum);
                }
            }
        }
        float v = fsum;
        v += __shfl_xor(v, 16);
        v += __shfl_xor(v, 32);
        if (lane < 16)
            out[(size_t)(r0 + l15) * T + (t - 1)] = v + bfc1[0];
    }

    // z tile -> per-wave LDS transpose (wave-local 16x32, row stride 144 B)
    char* zb = ze + w * 2304;
#pragma unroll
    for (int nt = 0; nt < 2; ++nt)
#pragma unroll
        for (int r = 0; r < 4; ++r)
            *(float*)(zb + (quad * 4 + r) * 144 + (nt * 16 + l15) * 4) = acc[nt][r];

    float* C = dir ? CB : CF;
    const int ul = lane & 7;
#pragma unroll
    for (int p2 = 0; p2 < 2; ++p2) {
        const int ml = p2 * 8 + (lane >> 3);
        const f32x4 z = *(const f32x4*)(zb + ml * 144 + ul * 16);
        const f32x4 b4 = *(const f32x4*)(BR + nbase + ul * 4);
        const float zi = z[0] + b4[0], zf = z[1] + b4[1];
        const float zg = z[2] + b4[2], zo = z[3] + b4[3];
        const int u = colgrp * 8 + ul;
        const int m = r0 + ml;
        const size_t cidx = (size_t)m * 1024 + u;
        const float cold = C[cidx];
        const float c2 = sigm(zf) * cold + sigm(zi) * tanhf(zg);
        const float h2 = sigm(zo) * tanhf(c2);
        C[cidx] = c2;
        const size_t hidx = (size_t)m * 2048 + dir * 1024 + u;
        const u16 hh = f2bf(h2);
        NAh[hidx] = hh;
        NAl[hidx] = f2bf(h2 - bf2f(hh));
    }
}

// ---------------------------------------------------------------------------
// k_tail: out[:, T-1] from final A planes. 128 blocks (one per row).
// ---------------------------------------------------------------------------
__global__ __launch_bounds__(256) void k_tail(
    const u16* __restrict__ Ah, const u16* __restrict__ Al,
    const float* __restrict__ Wfc1, const float* __restrict__ bfc1,
    float* __restrict__ out, int T)
{
    __shared__ float red[256];
    const int m = blockIdx.x, tid = threadIdx.x;
    const size_t base = (size_t)m * 2048 + tid * 8;
    const short8 hv = *(const short8*)(Ah + base);
    const short8 lv = *(const short8*)(Al + base);
    float s = 0.0f;
#pragma unroll
    for (int e = 0; e < 8; ++e) {
        const float v = bf2f((u16)hv[e]) + bf2f((u16)lv[e]);
        s = fmaf(fmaxf(v, 0.0f), Wfc1[tid * 8 + e], s);
    }
    red[tid] = s;
    __syncthreads();
    for (int off = 128; off > 0; off >>= 1) {
        if (tid < off) red[tid] += red[tid + off];
        __syncthreads();
    }
    if (tid == 0) out[(size_t)m * T + T - 1] = red[0] + bfc1[0];
}

// ---------------------------------------------------------------------------
// k_fold: W'[col'][1024+j] = (Wih' @ WoT^T)[col'][j]  (+ Whh_b for bwd cols)
// ---------------------------------------------------------------------------
__global__ __launch_bounds__(256, 1) void k_fold(
    const u16* __restrict__ AH, const u16* __restrict__ AL,   // Wih' 8192x512
    const u16* __restrict__ BH, const u16* __restrict__ BL,   // WoT 1024x512
    const float* __restrict__ Whh_b,
    u16* __restrict__ WH, u16* __restrict__ WL)
{
    const int tid = threadIdx.x, bid = blockIdx.x;
    const int w = tid >> 6, lane = tid & 63, l15 = lane & 15, quad = lane >> 4;
    const int bm = bid >> 4, bn = bid & 15;
    const int ar0 = bm * 64 + (w & 1) * 32;
    const int br0 = bn * 64 + (w >> 1) * 32;
    f32x4 acc[2][2] = {};
    for (int k0 = 0; k0 < 512; k0 += 32) {
        short8 a_h[2], a_l[2], b_h[2], b_l[2];
#pragma unroll
        for (int mt = 0; mt < 2; ++mt) {
            const size_t o = (size_t)(ar0 + mt * 16 + l15) * 512 + k0 + quad * 8;
            a_h[mt] = *(const short8*)(AH + o);
            a_l[mt] = *(const short8*)(AL + o);
        }
#pragma unroll
        for (int nt = 0; nt < 2; ++nt) {
            const size_t o = (size_t)(br0 + nt * 16 + l15) * 512 + k0 + quad * 8;
            b_h[nt] = *(const short8*)(BH + o);
            b_l[nt] = *(const short8*)(BL + o);
        }
#pragma unroll
        for (int mt = 0; mt < 2; ++mt)
#pragma unroll
            for (int nt = 0; nt < 2; ++nt) {
                acc[mt][nt] = mfma16(a_h[mt], b_h[nt], acc[mt][nt]);
                acc[mt][nt] = mfma16(a_l[mt], b_h[nt], acc[mt][nt]);
                acc[mt][nt] = mfma16(a_h[mt], b_l[nt], acc[mt][nt]);
            }
    }
#pragma unroll
    for (int mt = 0; mt < 2; ++mt)
#pragma unroll
        for (int nt = 0; nt < 2; ++nt)
#pragma unroll
            for (int r = 0; r < 4; ++r) {
                const int row = ar0 + mt * 16 + quad * 4 + r;   // col'
                const int j = br0 + nt * 16 + l15;
                float v = acc[mt][nt][r];
                if (row >= 4096)
                    v += Whh_b[(size_t)((row & 3) * 1024 + ((row & 4095) >> 2)) * 1024 + j];
                const size_t d = (size_t)row * 2048 + 1024 + j;
                const u16 hh = f2bf(v);
                WH[d] = hh;
                WL[d] = f2bf(v - bf2f(hh));
            }
}

// ---------------------------------------------------------------------------
// k_prep: Wih' hi/lo, WoT hi/lo, BR0/BR1, A0 (x=dec), out=b_fc1, Whh_f -> W'.
// ---------------------------------------------------------------------------
__global__ __launch_bounds__(256) void k_prep(
    const float* __restrict__ dec,
    const float* __restrict__ Wih_f, const float* __restrict__ Whh_f,
    const float* __restrict__ b_f, const float* __restrict__ Wih_b,
    const float* __restrict__ b_b, const float* __restrict__ W_out,
    const float* __restrict__ b_out, const float* __restrict__ b_fc1,
    u16* __restrict__ WihH, u16* __restrict__ WihL,
    u16* __restrict__ WoTH, u16* __restrict__ WoTL,
    float* __restrict__ BR0, float* __restrict__ BR1,
    u16* __restrict__ A0h, u16* __restrict__ A0l,
    u16* __restrict__ WH, u16* __restrict__ WL,
    float* __restrict__ out, int out_size)
{
    const int t = blockIdx.x * 256 + threadIdx.x;
    if (t < 524288) {                       // Wih' (gate-interleaved cols, K=512)
        const int colp = t >> 6, kb = (t & 63) * 8;
        const int dir = colp >> 12, u = (colp & 4095) >> 2, g = colp & 3;
        const float* src = (dir ? Wih_b : Wih_f) + (size_t)(g * 1024 + u) * 512 + kb;
        const size_t d = (size_t)colp * 512 + kb;
#pragma unroll
        for (int j = 0; j < 8; ++j) {
            const float v = src[j];
            const u16 hh = f2bf(v);
            WihH[d + j] = hh; WihL[d + j] = f2bf(v - bf2f(hh));
        }
    } else if (t < 589824) {                // WoT[j][l] = W_out[l][j]
        const int i = t - 524288, jc = i >> 6, lb = (i & 63) * 8;
#pragma unroll
        for (int jj = 0; jj < 8; ++jj) {
            const float v = W_out[(size_t)(lb + jj) * 1024 + jc];
            const size_t d = (size_t)jc * 512 + lb + jj;
            const u16 hh = f2bf(v);
            WoTH[d] = hh; WoTL[d] = f2bf(v - bf2f(hh));
        }
    } else if (t < 598016) {                // biases
        const int colp = t - 589824;
        const int dir = colp >> 12, u = (colp & 4095) >> 2, g = colp & 3;
        const float* Wih = dir ? Wih_b : Wih_f;
        const float s = (dir ? b_b : b_f)[g * 1024 + u];
        BR0[colp] = s;
        float dot = 0.0f;
        for (int l = 0; l < 512; ++l)
            dot += Wih[(size_t)(g * 1024 + u) * 512 + l] * b_out[l];
        BR1[colp] = s + dot;
    } else if (t < 606208) {                // A0 = dec (cols [0,512), stride 2048)
        const int i = t - 598016, m = i >> 6, kb = (i & 63) * 8;
#pragma unroll
        for (int j = 0; j < 8; ++j) {
            const float v = dec[(size_t)m * 512 + kb + j];
            const size_t d = (size_t)m * 2048 + kb + j;
            const u16 hh = f2bf(v);
            A0h[d] = hh; A0l[d] = f2bf(v - bf2f(hh));
        }
    } else if (t < 614400) {                // out init = b_fc1 (safety net)
        const int base = (t - 606208) * 8;
        const float b0 = b_fc1[0];
#pragma unroll
        for (int j = 0; j < 8; ++j)
            if (base + j < out_size) out[base + j] = b0;
    } else {                                // Whh_f -> W' fwd cols, k in [0,1024)
        const int i = t - 614400, colp = i >> 7, kb = (i & 127) * 8;
        const int u = colp >> 2, g = colp & 3;
        const float* src = Whh_f + (size_t)(g * 1024 + u) * 1024 + kb;
        const size_t d = (size_t)colp * 2048 + kb;
#pragma unroll
        for (int j = 0; j < 8; ++j) {
            const float v = src[j];
            const u16 hh = f2bf(v);
            WH[d + j] = hh; WL[d + j] = f2bf(v - bf2f(hh));
        }
    }
}

// ---------------------------------------------------------------------------
// ws layout unchanged from baseline.
// ---------------------------------------------------------------------------
extern "C" void kernel_launch(void* const* d_in, const int* in_sizes, int n_in,
                              void* d_out, int out_size, void* d_ws, size_t ws_size,
                              hipStream_t stream) {
    const float* dec   = (const float*)d_in[0];
    const float* Wih_f = (const float*)d_in[2];
    const float* Whh_f = (const float*)d_in[3];
    const float* b_f   = (const float*)d_in[4];
    const float* Wih_b = (const float*)d_in[5];
    const float* Whh_b = (const float*)d_in[6];
    const float* b_b   = (const float*)d_in[7];
    const float* W_out = (const float*)d_in[8];
    const float* b_out = (const float*)d_in[9];
    const float* W_fc1 = (const float*)d_in[10];
    const float* b_fc1 = (const float*)d_in[11];
    float* out = (float*)d_out;

    char* ws = (char*)d_ws;
    u16* WH    = (u16*)(ws);
    u16* WL    = (u16*)(ws + 33554432);
    u16* WihH  = (u16*)(ws + 67108864);
    u16* WihL  = (u16*)(ws + 75497472);
    u16* WoTH  = (u16*)(ws + 83886080);
    u16* WoTL  = (u16*)(ws + 84934656);
    u16* A0h   = (u16*)(ws + 85983232);
    u16* A0l   = (u16*)(ws + 86507520);
    u16* A1h   = (u16*)(ws + 87031808);
    u16* A1l   = (u16*)(ws + 87556096);
    float* CF  = (float*)(ws + 88080384);
    float* CB  = (float*)(ws + 88604672);
    float* BR0 = (float*)(ws + 89128960);
    float* BR1 = (float*)(ws + 89161728);

    k_prep<<<4448, 256, 0, stream>>>(dec, Wih_f, Whh_f, b_f, Wih_b, b_b,
                                     W_out, b_out, b_fc1,
                                     WihH, WihL, WoTH, WoTL, BR0, BR1,
                                     A0h, A0l, WH, WL, out, out_size);
    k_fold<<<2048, 256, 0, stream>>>(WihH, WihL, WoTH, WoTL, Whh_b, WH, WL);
    hipMemsetAsync(CF, 0, 1048576, stream);   // CF + CB contiguous

    const int T = out_size / 128;
    u16* Abh[2] = {A0h, A1h};
    u16* Abl[2] = {A0l, A1l};
    for (int t = 0; t < T; ++t) {
        const int in = t & 1, nx = in ^ 1;
        if (t == 0) {
            k_step<<<512, 256, 0, stream>>>(A0h, A0l, A1h, A1l,
                                            WihH, WihL, 512, 0, 8, 0, 8,
                                            BR0, CF, CB, W_fc1, b_fc1, out, T, 0);
        } else {
            k_step<<<512, 256, 0, stream>>>(Abh[in], Abl[in], Abh[nx], Abl[nx],
                                            WH, WL, 2048, 0, 32, 1024, 16,
                                            BR1, CF, CB, W_fc1, b_fc1, out, T, t);
        }
    }
    k_tail<<<128, 256, 0, stream>>>(Abh[T & 1], Abl[T & 1], W_fc1, b_fc1, out, T);
}